// Round 4
// baseline (296.206 us; speedup 1.0000x reference)
//
#include <hip/hip_runtime.h>
#include <math.h>

#define NROWS 16384
#define DIN   1024
#define DEMB  256
#define KC    1024
#define ALPHA 0.01f
#define EPSV  1e-5f
#define INV2048 4.8828125e-4f
#define CHUNK 32
#define COV_CHUNKS 8

typedef _Float16 f16;
typedef __attribute__((ext_vector_type(4)))  _Float16 f16x4;
typedef __attribute__((ext_vector_type(8)))  _Float16 f16x8;
typedef __attribute__((ext_vector_type(16))) float    f32x16;
typedef unsigned long long u64;

// ---- workspace layout (float-element offsets, 16-aligned) ----
#define OFF_Z       0          // NROWS*DEMB = 4194304 (fp32 z)
#define OFF_R       4194304    // KC*DIN = 1048576
#define OFF_SQR     5242880    // KC
#define OFF_ZH      5243904    // NROWS*DEMB f16 = 2097152 floats
#define OFF_ZL      7341056    // 2097152
#define OFF_WTH     9438208    // DEMB*DIN f16 = 131072 floats
#define OFF_WTL     9569280    // 131072
#define OFF_CBH     9700352    // KC*DEMB f16 = 131072 floats
#define OFF_CBL     9831424    // 131072
#define OFF_KEYS    9962496    // NROWS u64 = 32768 floats (memset 0xFF)
#define OFF_CODES   9995264    // NROWS ints
#define OFF_LIST    10011648   // NROWS ints (bucketed row ids)
#define OFF_OFFS    10028032   // KC ints (exclusive prefix)
#define OFF_UPD     10029056   // KC*DEMB = 262144 (zeroed: atomic target)
#define OFF_HIST    10291200   // KC ints   (zeroed)
#define OFF_CURSOR  10292224   // KC ints   (zeroed)
#define OFF_LOSS    10293248   // 16        (zeroed)
#define ZERO_LEN    264208     // UPD+HIST+CURSOR+LOSS contiguous
#define OFF_COUNTSF 10293264   // KC floats
#define OFF_SIZE    10294288   // KC floats
// total 10295312 floats ~41.2 MB

// ---- output layout (float-element offsets) ----
#define OUT_X      0           // NROWS*DIN
#define OUT_CODES  16777216    // NROWS
#define OUT_EMB    16793600
#define OUT_COMMIT 16793601
#define OUT_ENT    16793602
#define OUT_EMAV   16793603    // KC*DEMB
#define OUT_EMAS   17055747    // KC
#define OUT_W      17056771    // KC*DEMB

__device__ __forceinline__ void split_f32(float x, f16& h, f16& l) {
    h = (f16)x;
    l = (f16)((x - (float)h) * 2048.0f);
}

// ---------------------------------------------------------------------------
__global__ __launch_bounds__(64) void sqr_kernel(const float* __restrict__ cb,
                                                 float* __restrict__ sqr) {
    int k = blockIdx.x;
    int lane = threadIdx.x;
    float4 v = ((const float4*)cb)[k * 64 + lane];
    float s = v.x * v.x + v.y * v.y + v.z * v.z + v.w * v.w;
    for (int off = 32; off > 0; off >>= 1) s += __shfl_down(s, off, 64);
    if (lane == 0) sqr[k] = s;
}

// ---------------------------------------------------------------------------
// W_send [1024,256] -> WT_hi/WT_lo [256][1024] (transposed, f16 split)
__global__ __launch_bounds__(256) void split_wt_kernel(const float* __restrict__ W,
                                                       f16* __restrict__ wth,
                                                       f16* __restrict__ wtl) {
    int n = blockIdx.x;
    int t = threadIdx.x;
    f16x4 h4, l4;
#pragma unroll
    for (int j = 0; j < 4; ++j) {
        int k = t * 4 + j;
        float x = W[(size_t)k * DEMB + n];
        f16 h, l; split_f32(x, h, l);
        h4[j] = h; l4[j] = l;
    }
    *(f16x4*)&wth[(size_t)n * DIN + t * 4] = h4;
    *(f16x4*)&wtl[(size_t)n * DIN + t * 4] = l4;
}

// ---------------------------------------------------------------------------
__global__ __launch_bounds__(256) void split_cb_kernel(const float* __restrict__ cb,
                                                       f16* __restrict__ cbh,
                                                       f16* __restrict__ cbl) {
    int idx = (blockIdx.x * 256 + threadIdx.x) * 4;
    float4 v = *(const float4*)&cb[idx];
    f16x4 h4, l4;
    f16 h, l;
    split_f32(v.x, h, l); h4[0] = h; l4[0] = l;
    split_f32(v.y, h, l); h4[1] = h; l4[1] = l;
    split_f32(v.z, h, l); h4[2] = h; l4[2] = l;
    split_f32(v.w, h, l); h4[3] = h; l4[3] = l;
    *(f16x4*)&cbh[idx] = h4;
    *(f16x4*)&cbl[idx] = l4;
}

// ---------------------------------------------------------------------------
// z = input @ W_send + b_send via f16x3 MFMA (32x32x16), + z hi/lo split out.
// v4: m97-style 2-barrier single-buffer loop, 64x64 tile, BK=64, 256 thr
//     (2x2 waves), 32 KB LDS -> grid (4,256)=1024 blocks = 4 blocks/CU =
//     16 waves/CU. Barrier drains hidden by 3 co-resident blocks (m114).
//     B staged async via global_load_lds (inverse-swizzled source, rule #21);
//     A reg-staged split + XOR slot^(row&7) ds_write (conflict-free per
//     8-lane batch; 128B row stride -> quad == slot).
//     K-seg order & MFMA sequence identical to v1..v3 -> z bit-identical.
__global__ __launch_bounds__(256, 4) void gemm1_mfma(const float* __restrict__ in,
                                                     const f16* __restrict__ wth,
                                                     const f16* __restrict__ wtl,
                                                     const float* __restrict__ bsend,
                                                     float* __restrict__ z,
                                                     f16* __restrict__ zh,
                                                     f16* __restrict__ zl) {
    // f16 offsets: Ah [0,4096) Al [4096,8192) Bh [8192,12288) Bl [12288,16384)
    __shared__ f16 sm[16384];   // 32 KB
    const int tid = threadIdx.x;
    const int wave = tid >> 6, lane = tid & 63;
    const int half = lane >> 5, l31 = lane & 31;
    const int wr = wave >> 1, wc = wave & 1;
    const int rowBase = blockIdx.y * 64;
    const int colBase = blockIdx.x * 64;

    const int sr  = tid >> 2;    // staging row 0..63
    const int skq = tid & 3;     // staging k-quarter (16 floats)
    const int sr7 = sr & 7;

    f32x16 accm = {};
    f32x16 accx = {};

    for (int step = 0; step < 16; ++step) {
        const int ks = step * 64;

        // ---- B stage: 16 chunks of 1 KB (8 cols x 8 slots), 4 per wave ----
#pragma unroll
        for (int i = 0; i < 4; ++i) {
            const int q  = wave * 4 + i;          // 0..15
            const int hl = q >> 3;
            const int cq = (q & 7) * 8;           // col group base
            const int col = cq + (lane >> 3);
            const int p  = lane & 7;              // physical 16B slot
            const int s  = p ^ (col & 7);         // logical slot (inv swizzle)
            const f16* src = (hl ? wtl : wth)
                           + (size_t)(colBase + col) * DIN + ks + s * 8;
            f16* dst = sm + 8192 + hl * 4096 + cq * 64;   // wave-uniform
            __builtin_amdgcn_global_load_lds(
                (const __attribute__((address_space(1))) void*)src,
                (__attribute__((address_space(3))) void*)dst, 16, 0, 0);
        }

        // ---- A stage: 16 floats/thread -> split -> swizzled ds_write ----
        {
            const float* srcp = &in[(size_t)(rowBase + sr) * DIN + ks + skq * 16];
            float4 av0 = ((const float4*)srcp)[0];
            float4 av1 = ((const float4*)srcp)[1];
            float4 av2 = ((const float4*)srcp)[2];
            float4 av3 = ((const float4*)srcp)[3];
            f16 h, l;
            f16x8 h8, l8;
            split_f32(av0.x, h, l); h8[0] = h; l8[0] = l;
            split_f32(av0.y, h, l); h8[1] = h; l8[1] = l;
            split_f32(av0.z, h, l); h8[2] = h; l8[2] = l;
            split_f32(av0.w, h, l); h8[3] = h; l8[3] = l;
            split_f32(av1.x, h, l); h8[4] = h; l8[4] = l;
            split_f32(av1.y, h, l); h8[5] = h; l8[5] = l;
            split_f32(av1.z, h, l); h8[6] = h; l8[6] = l;
            split_f32(av1.w, h, l); h8[7] = h; l8[7] = l;
            const int o0 = sr * 64 + (((2 * skq + 0) ^ sr7) << 3);
            *(f16x8*)&sm[o0] = h8;
            *(f16x8*)&sm[4096 + o0] = l8;

            split_f32(av2.x, h, l); h8[0] = h; l8[0] = l;
            split_f32(av2.y, h, l); h8[1] = h; l8[1] = l;
            split_f32(av2.z, h, l); h8[2] = h; l8[2] = l;
            split_f32(av2.w, h, l); h8[3] = h; l8[3] = l;
            split_f32(av3.x, h, l); h8[4] = h; l8[4] = l;
            split_f32(av3.y, h, l); h8[5] = h; l8[5] = l;
            split_f32(av3.z, h, l); h8[6] = h; l8[6] = l;
            split_f32(av3.w, h, l); h8[7] = h; l8[7] = l;
            const int o1 = sr * 64 + (((2 * skq + 1) ^ sr7) << 3);
            *(f16x8*)&sm[o1] = h8;
            *(f16x8*)&sm[4096 + o1] = l8;
        }

        __syncthreads();   // stage visible (compiler drains vmcnt/lgkm)

        // ---- compute: 4 k-segs x 3 MFMA ----
        {
            const int r = wr * 32 + l31;
            const int c = wc * 32 + l31;
            const int r7 = r & 7, c7 = c & 7;
#pragma unroll
            for (int t = 0; t < 4; ++t) {
                const int sgi = t * 2 + half;
                const int aoff = r * 64 + ((sgi ^ r7) << 3);
                const int boff = c * 64 + ((sgi ^ c7) << 3);
                f16x8 a_h = *(const f16x8*)&sm[aoff];
                f16x8 a_l = *(const f16x8*)&sm[4096 + aoff];
                f16x8 b_h = *(const f16x8*)&sm[8192 + boff];
                f16x8 b_l = *(const f16x8*)&sm[12288 + boff];
                accm = __builtin_amdgcn_mfma_f32_32x32x16_f16(a_h, b_h, accm, 0, 0, 0);
                accx = __builtin_amdgcn_mfma_f32_32x32x16_f16(a_h, b_l, accx, 0, 0, 0);
                accx = __builtin_amdgcn_mfma_f32_32x32x16_f16(a_l, b_h, accx, 0, 0, 0);
            }
        }

        __syncthreads();   // compute done; LDS reusable next step
    }

    // ---- epilogue ----
    {
        const int col = colBase + wc * 32 + l31;
        const float bb = bsend[col];
#pragma unroll
        for (int reg = 0; reg < 16; ++reg) {
            const int row = rowBase + wr * 32 + (reg & 3) + 8 * (reg >> 2) + 4 * half;
            const float zv = accm[reg] + INV2048 * accx[reg] + bb;
            const size_t o = (size_t)row * DEMB + col;
            z[o] = zv;
            f16 h = (f16)zv;
            zh[o] = h;
            zl[o] = (f16)((zv - (float)h) * 2048.0f);
        }
    }
}

// ---------------------------------------------------------------------------
// cov + argmin via f16x3 MFMA — (unchanged structure from round 1)
__device__ __forceinline__ void cov_stage(const f16* __restrict__ cbh,
                                          const f16* __restrict__ cbl,
                                          f16* sC, int buf, int codeBase,
                                          int wave, int lane) {
#pragma unroll
    for (int i = 0; i < 8; ++i) {
        const int seg = wave * 8 + i;          // 0..31
        const int hl  = seg >> 4;              // 0: hi array, 1: lo array
        const int rp  = seg & 15;              // row pair
        const int r   = rp * 2 + (lane >> 5);  // 0..31 (per-lane row)
        const f16* src = (hl ? cbl : cbh)
                       + (size_t)(codeBase + r) * DEMB
                       + (((lane & 31) ^ r) << 3);
        f16* dst = sC + (((buf << 1) + hl) * 32 + rp * 2) * DEMB;  // wave-uniform
        __builtin_amdgcn_global_load_lds(
            (const __attribute__((address_space(1))) void*)src,
            (__attribute__((address_space(3))) void*)dst,
            16, 0, 0);
    }
}

__global__ __launch_bounds__(256, 2) void cov_mfma_kernel(const f16* __restrict__ zh,
                                                          const f16* __restrict__ zl,
                                                          const f16* __restrict__ cbh,
                                                          const f16* __restrict__ cbl,
                                                          const float* __restrict__ sqr,
                                                          u64* __restrict__ keys) {
    __shared__ f16 sC[2 * 2 * 32 * DEMB];   // 64 KB: [buf][hi/lo][code][dim swz]
    const int tid = threadIdx.x;
    const int wave = tid >> 6, lane = tid & 63;
    const int half = lane >> 5, l31 = lane & 31;
    const int rowBase = blockIdx.y * 128 + wave * 32;
    const int myRow = rowBase + l31;
    const int cb0 = blockIdx.x * (COV_CHUNKS * 32);   // 256 codes per block

    cov_stage(cbh, cbl, sC, 0, cb0, wave, lane);

    f16x8 a_h[16], a_l[16];
#pragma unroll
    for (int t = 0; t < 16; ++t) {
        size_t o = (size_t)myRow * DEMB + t * 16 + half * 8;
        a_h[t] = *(const f16x8*)&zh[o];
        a_l[t] = *(const f16x8*)&zl[o];
    }

    float runv[16];
    int   runc[16];
#pragma unroll
    for (int r = 0; r < 16; ++r) { runv[r] = 3.4e38f; runc[r] = 0; }

    for (int cc = 0; cc < COV_CHUNKS; ++cc) {
        __syncthreads();
        if (cc + 1 < COV_CHUNKS)
            cov_stage(cbh, cbl, sC, (cc + 1) & 1, cb0 + (cc + 1) * 32, wave, lane);

        const f16* Ch = sC + ((cc & 1) * 2 + 0) * 32 * DEMB;
        const f16* Cl = sC + ((cc & 1) * 2 + 1) * 32 * DEMB;

        f32x16 accm = {};
        f32x16 accx = {};
#pragma unroll
        for (int t = 0; t < 16; ++t) {
            const int seg = t * 2 + half;
            const int p = ((seg ^ l31) << 3);
            f16x8 b_h = *(const f16x8*)&Ch[l31 * DEMB + p];
            f16x8 b_l = *(const f16x8*)&Cl[l31 * DEMB + p];
            accm = __builtin_amdgcn_mfma_f32_32x32x16_f16(a_h[t], b_h, accm, 0, 0, 0);
            accx = __builtin_amdgcn_mfma_f32_32x32x16_f16(a_h[t], b_l, accx, 0, 0, 0);
            accx = __builtin_amdgcn_mfma_f32_32x32x16_f16(a_l[t], b_h, accx, 0, 0, 0);
        }

        const int code = cb0 + cc * 32 + l31;
        const float sqv = sqr[code];
#pragma unroll
        for (int r = 0; r < 16; ++r) {
            float s = sqv - 2.0f * (accm[r] + INV2048 * accx[r]);
            if (s < runv[r]) { runv[r] = s; runc[r] = code; }
        }
    }

#pragma unroll
    for (int r = 0; r < 16; ++r) {
        float v = runv[r]; int ci = runc[r];
        for (int off = 16; off > 0; off >>= 1) {
            float ov = __shfl_down(v, off, 32);
            int   oc = __shfl_down(ci, off, 32);
            if (ov < v || (ov == v && oc < ci)) { v = ov; ci = oc; }
        }
        if (l31 == 0) {
            int row = rowBase + (r & 3) + 8 * (r >> 2) + 4 * half;
            unsigned ub = __float_as_uint(v);
            ub = (ub & 0x80000000u) ? ~ub : (ub | 0x80000000u);
            u64 key = ((u64)ub << 32) | (unsigned)ci;
            atomicMin(&keys[row], key);
        }
    }
}

// ---------------------------------------------------------------------------
// decode keys -> codes (+float codes out) and build histogram
__global__ __launch_bounds__(256) void decode_kernel(const u64* __restrict__ keys,
                                                     int* __restrict__ codes,
                                                     float* __restrict__ out_codes,
                                                     int* __restrict__ hist) {
    int r = blockIdx.x * 256 + threadIdx.x;
    int c = (int)(keys[r] & 0xFFFFFFFFull);
    codes[r] = c;
    out_codes[r] = (float)c;
    atomicAdd(&hist[c], 1);
}

// ---------------------------------------------------------------------------
// exclusive prefix over hist (1 block of 1024); also counts as float
__global__ __launch_bounds__(1024) void prefix_kernel(const int* __restrict__ hist,
                                                      int* __restrict__ offs,
                                                      float* __restrict__ countsf) {
    __shared__ int s[1024];
    int t = threadIdx.x;
    int v = hist[t];
    s[t] = v;
    countsf[t] = (float)v;
    __syncthreads();
    for (int d = 1; d < 1024; d <<= 1) {
        int x = (t >= d) ? s[t - d] : 0;
        __syncthreads();
        s[t] += x;
        __syncthreads();
    }
    offs[t] = s[t] - v;
}

// ---------------------------------------------------------------------------
__global__ __launch_bounds__(256) void fill_kernel(const int* __restrict__ codes,
                                                   const int* __restrict__ offs,
                                                   int* __restrict__ cursor,
                                                   int* __restrict__ list) {
    int r = blockIdx.x * 256 + threadIdx.x;
    int c = codes[r];
    int pos = offs[c] + atomicAdd(&cursor[c], 1);
    list[pos] = r;
}

// ---------------------------------------------------------------------------
// balanced segment-sum over the sorted list: 32 list entries per block,
// 256 thr = 1 dim each. Register partial per run; atomicAdd flush at run
// boundaries (wave-uniform). Also accumulates commitment loss.
__global__ __launch_bounds__(256) void upd_loss_kernel(const float* __restrict__ z,
                                                       const float* __restrict__ cb,
                                                       const int* __restrict__ list,
                                                       const int* __restrict__ codes,
                                                       float* __restrict__ upd,
                                                       float* __restrict__ loss) {
    __shared__ int srow[CHUNK];
    __shared__ int scode[CHUNK];
    const int tid = threadIdx.x;
    const int base = blockIdx.x * CHUNK;
    if (tid < CHUNK) {
        int r = list[base + tid];
        srow[tid] = r;
        scode[tid] = codes[r];
    }
    __syncthreads();

    int cur = scode[0];
    float cbv = cb[(size_t)cur * DEMB + tid];
    float acc = 0.f, lacc = 0.f;
    float zv = z[(size_t)srow[0] * DEMB + tid];
#pragma unroll 4
    for (int i = 0; i < CHUNK; ++i) {
        float znext = (i + 1 < CHUNK) ? z[(size_t)srow[i + 1] * DEMB + tid] : 0.f;
        int c = scode[i];
        if (c != cur) {                         // wave-uniform branch
            atomicAdd(&upd[(size_t)cur * DEMB + tid], acc);
            acc = 0.f;
            cur = c;
            cbv = cb[(size_t)cur * DEMB + tid];
        }
        acc += zv;
        float d = zv - cbv;
        lacc += d * d;
        zv = znext;
    }
    atomicAdd(&upd[(size_t)cur * DEMB + tid], acc);

    __shared__ float red[256];
    red[tid] = lacc;
    __syncthreads();
    for (int s = 128; s > 0; s >>= 1) {
        if (tid < s) red[tid] += red[tid + s];
        __syncthreads();
    }
    if (tid == 0) atomicAdd(loss, red[0]);
}

// ---------------------------------------------------------------------------
// 64x64-tile fp32 GEMM (R = codebook @ W_recv)
__global__ __launch_bounds__(256) void gemm64_kernel(const float* __restrict__ A,
                                                     const float* __restrict__ B,
                                                     float* __restrict__ C,
                                                     int M, int Kd, int Nc) {
    __shared__ float As[16][68];
    __shared__ float Bs[16][64];
    const int tid = threadIdx.x;
    const int tx = tid & 15, ty = tid >> 4;
    const int rowBase = blockIdx.y * 64;
    const int colBase = blockIdx.x * 64;

    float acc[4][4];
#pragma unroll
    for (int i = 0; i < 4; ++i)
#pragma unroll
        for (int j = 0; j < 4; ++j) acc[i][j] = 0.f;

    const int a_row = tid >> 2;
    const int a_c4  = (tid & 3) * 4;
    const int b_r   = tid >> 4;
    const int b_c4  = (tid & 15) * 4;

    for (int kk = 0; kk < Kd; kk += 16) {
        float4 av = *(const float4*)&A[(size_t)(rowBase + a_row) * Kd + kk + a_c4];
        float4 bv = *(const float4*)&B[(size_t)(kk + b_r) * Nc + colBase + b_c4];
        __syncthreads();
        As[a_c4 + 0][a_row] = av.x;  As[a_c4 + 1][a_row] = av.y;
        As[a_c4 + 2][a_row] = av.z;  As[a_c4 + 3][a_row] = av.w;
        *(float4*)&Bs[b_r][b_c4] = bv;
        __syncthreads();
#pragma unroll
        for (int d = 0; d < 16; ++d) {
            float4 a01 = *(const float4*)&As[d][ty * 4];
            float4 b01 = *(const float4*)&Bs[d][tx * 4];
            float a[4] = {a01.x, a01.y, a01.z, a01.w};
            float b[4] = {b01.x, b01.y, b01.z, b01.w};
#pragma unroll
            for (int i = 0; i < 4; ++i)
#pragma unroll
                for (int j = 0; j < 4; ++j) acc[i][j] += a[i] * b[j];
        }
    }

#pragma unroll
    for (int i = 0; i < 4; ++i) {
        int r = rowBase + ty * 4 + i;
        *(float4*)&C[(size_t)r * Nc + colBase + tx * 4] =
            make_float4(acc[i][0], acc[i][1], acc[i][2], acc[i][3]);
    }
}

// ---------------------------------------------------------------------------
__global__ __launch_bounds__(256) void recv_kernel(const float* __restrict__ R,
                                                   const float* __restrict__ brecv,
                                                   const int* __restrict__ codes,
                                                   float* __restrict__ out) {
    const int n = blockIdx.x;
    const int t = threadIdx.x;
    const int code = codes[n];
    float4 r = ((const float4*)(R + (size_t)code * DIN))[t];
    float4 b = ((const float4*)brecv)[t];
    ((float4*)(out + (size_t)n * DIN))[t] =
        make_float4(r.x + b.x, r.y + b.y, r.z + b.z, r.w + b.w);
}

// ---------------------------------------------------------------------------
__global__ __launch_bounds__(1024) void ema_small_kernel(const float* __restrict__ ema_size,
                                                         const float* __restrict__ counts,
                                                         const float* __restrict__ loss,
                                                         float* __restrict__ size_ws,
                                                         float* __restrict__ out) {
    __shared__ float rn[1024];
    __shared__ float re[1024];
    const int k = threadIdx.x;
    float c  = counts[k];
    float es = ema_size[k];
    float esn = es + ALPHA * (c - es);
    out[OUT_EMAS + k] = esn;
    float p = c * (1.0f / (float)NROWS);
    rn[k] = esn;
    re[k] = (p > 0.f) ? p * logf(p) : 0.f;
    __syncthreads();
    for (int s = 512; s > 0; s >>= 1) {
        if (k < s) { rn[k] += rn[k + s]; re[k] += re[k + s]; }
        __syncthreads();
    }
    float n = rn[0];
    float coef = n / (n + (float)KC * EPSV);
    size_ws[k] = coef * (esn + EPSV);
    if (k == 0) {
        out[OUT_ENT] = -re[0] / logf(2.0f);
        float l = loss[0];
        out[OUT_EMB] = l;
        out[OUT_COMMIT] = l;
    }
}

// ---------------------------------------------------------------------------
__global__ __launch_bounds__(256) void emav_kernel(const float* __restrict__ ema_vecs,
                                                   const float* __restrict__ upd,
                                                   const float* __restrict__ size_ws,
                                                   float* __restrict__ out) {
    int idx = blockIdx.x * 256 + threadIdx.x;
    float ev = ema_vecs[idx], uv = upd[idx];
    float evn = ev + ALPHA * (uv - ev);
    out[OUT_EMAV + idx] = evn;
    out[OUT_W + idx] = evn / size_ws[idx >> 8];
}

// ---------------------------------------------------------------------------
extern "C" void kernel_launch(void* const* d_in, const int* in_sizes, int n_in,
                              void* d_out, int out_size, void* d_ws, size_t ws_size,
                              hipStream_t stream) {
    const float* input    = (const float*)d_in[0];
    const float* W_send   = (const float*)d_in[1];
    const float* b_send   = (const float*)d_in[2];
    const float* W_recv   = (const float*)d_in[3];
    const float* b_recv   = (const float*)d_in[4];
    const float* codebook = (const float*)d_in[5];
    const float* ema_vecs = (const float*)d_in[6];
    const float* ema_size = (const float*)d_in[7];
    float* out = (float*)d_out;
    float* ws  = (float*)d_ws;
    int*   wsi = (int*)d_ws;

    f16* wth = (f16*)(ws + OFF_WTH);
    f16* wtl = (f16*)(ws + OFF_WTL);
    f16* cbh = (f16*)(ws + OFF_CBH);
    f16* cbl = (f16*)(ws + OFF_CBL);
    f16* zh  = (f16*)(ws + OFF_ZH);
    f16* zl  = (f16*)(ws + OFF_ZL);
    u64* keys = (u64*)(ws + OFF_KEYS);

    // zero upd+hist+cursor+loss; keys to all-ones
    (void)hipMemsetAsync(ws + OFF_UPD, 0, (size_t)ZERO_LEN * sizeof(float), stream);
    (void)hipMemsetAsync(ws + OFF_KEYS, 0xFF, (size_t)NROWS * sizeof(u64), stream);

    sqr_kernel<<<KC, 64, 0, stream>>>(codebook, ws + OFF_SQR);
    split_wt_kernel<<<DEMB, 256, 0, stream>>>(W_send, wth, wtl);
    split_cb_kernel<<<256, 256, 0, stream>>>(codebook, cbh, cbl);

    // R = codebook @ W_recv (fp32)
    gemm64_kernel<<<dim3(DIN / 64, KC / 64), 256, 0, stream>>>(
        codebook, W_recv, ws + OFF_R, KC, DEMB, DIN);

    // z = input @ W_send + b_send (f16x3 MFMA) + fused hi/lo split
    gemm1_mfma<<<dim3(DEMB / 64, NROWS / 64), 256, 0, stream>>>(
        input, wth, wtl, b_send, ws + OFF_Z, zh, zl);

    // cov + fused argmin
    cov_mfma_kernel<<<dim3(KC / (COV_CHUNKS * 32), NROWS / 128), 256, 0, stream>>>(
        zh, zl, cbh, cbl, ws + OFF_SQR, keys);

    decode_kernel<<<NROWS / 256, 256, 0, stream>>>(
        keys, wsi + OFF_CODES, out + OUT_CODES, wsi + OFF_HIST);

    prefix_kernel<<<1, 1024, 0, stream>>>(
        wsi + OFF_HIST, wsi + OFF_OFFS, ws + OFF_COUNTSF);

    fill_kernel<<<NROWS / 256, 256, 0, stream>>>(
        wsi + OFF_CODES, wsi + OFF_OFFS, wsi + OFF_CURSOR, wsi + OFF_LIST);

    upd_loss_kernel<<<NROWS / CHUNK, 256, 0, stream>>>(
        ws + OFF_Z, codebook, wsi + OFF_LIST, wsi + OFF_CODES,
        ws + OFF_UPD, ws + OFF_LOSS);

    recv_kernel<<<NROWS, 256, 0, stream>>>(
        ws + OFF_R, b_recv, wsi + OFF_CODES, out + OUT_X);

    ema_small_kernel<<<1, 1024, 0, stream>>>(
        ema_size, ws + OFF_COUNTSF, ws + OFF_LOSS, ws + OFF_SIZE, out);

    emav_kernel<<<KC, 256, 0, stream>>>(
        ema_vecs, ws + OFF_UPD, ws + OFF_SIZE, out);
}

// Round 5
// 275.166 us; speedup vs baseline: 1.0765x; 1.0765x over previous
//
#include <hip/hip_runtime.h>
#include <math.h>

#define NROWS 16384
#define DIN   1024
#define DEMB  256
#define KC    1024
#define ALPHA 0.01f
#define EPSV  1e-5f
#define INV2048 4.8828125e-4f
#define CHUNK 32
#define COV_CHUNKS 8

typedef _Float16 f16;
typedef __attribute__((ext_vector_type(4)))  _Float16 f16x4;
typedef __attribute__((ext_vector_type(8)))  _Float16 f16x8;
typedef __attribute__((ext_vector_type(16))) float    f32x16;
typedef unsigned long long u64;

// ---- workspace layout (float-element offsets, 16-aligned) ----
#define OFF_Z       0          // NROWS*DEMB = 4194304 (fp32 z)
#define OFF_R       4194304    // KC*DIN = 1048576
#define OFF_SQR     5242880    // KC
#define OFF_ZH      5243904    // NROWS*DEMB f16 = 2097152 floats
#define OFF_ZL      7341056    // 2097152
#define OFF_WTH     9438208    // DEMB*DIN f16 = 131072 floats
#define OFF_WTL     9569280    // 131072
#define OFF_CBH     9700352    // KC*DEMB f16 = 131072 floats
#define OFF_CBL     9831424    // 131072
#define OFF_KEYS    9962496    // NROWS u64 = 32768 floats (memset 0xFF)
#define OFF_CODES   9995264    // NROWS ints
#define OFF_LIST    10011648   // NROWS ints (bucketed row ids)
#define OFF_OFFS    10028032   // KC ints (exclusive prefix)
#define OFF_UPD     10029056   // KC*DEMB = 262144 (zeroed: atomic target)
#define OFF_HIST    10291200   // KC ints   (zeroed)
#define OFF_CURSOR  10292224   // KC ints   (zeroed)
#define OFF_LOSS    10293248   // 16        (zeroed)
#define ZERO_LEN    264208     // UPD+HIST+CURSOR+LOSS contiguous
#define OFF_COUNTSF 10293264   // KC floats
#define OFF_SIZE    10294288   // KC floats
// wrh/wrl (split W_recv, 1024x256 f16 each = 131072 floats total x2) are
// parked in the ZH region: consumed by gemm2 BEFORE gemm1 overwrites zh.

// ---- output layout (float-element offsets) ----
#define OUT_X      0           // NROWS*DIN
#define OUT_CODES  16777216    // NROWS
#define OUT_EMB    16793600
#define OUT_COMMIT 16793601
#define OUT_ENT    16793602
#define OUT_EMAV   16793603    // KC*DEMB
#define OUT_EMAS   17055747    // KC
#define OUT_W      17056771    // KC*DEMB

__device__ __forceinline__ void split_f32(float x, f16& h, f16& l) {
    h = (f16)x;
    l = (f16)((x - (float)h) * 2048.0f);
}

// ---------------------------------------------------------------------------
__global__ __launch_bounds__(64) void sqr_kernel(const float* __restrict__ cb,
                                                 float* __restrict__ sqr) {
    int k = blockIdx.x;
    int lane = threadIdx.x;
    float4 v = ((const float4*)cb)[k * 64 + lane];
    float s = v.x * v.x + v.y * v.y + v.z * v.z + v.w * v.w;
    for (int off = 32; off > 0; off >>= 1) s += __shfl_down(s, off, 64);
    if (lane == 0) sqr[k] = s;
}

// ---------------------------------------------------------------------------
// W_send [1024,256] -> WT_hi/WT_lo [256][1024] (transposed, f16 split)
__global__ __launch_bounds__(256) void split_wt_kernel(const float* __restrict__ W,
                                                       f16* __restrict__ wth,
                                                       f16* __restrict__ wtl) {
    int n = blockIdx.x;
    int t = threadIdx.x;
    f16x4 h4, l4;
#pragma unroll
    for (int j = 0; j < 4; ++j) {
        int k = t * 4 + j;
        float x = W[(size_t)k * DEMB + n];
        f16 h, l; split_f32(x, h, l);
        h4[j] = h; l4[j] = l;
    }
    *(f16x4*)&wth[(size_t)n * DIN + t * 4] = h4;
    *(f16x4*)&wtl[(size_t)n * DIN + t * 4] = l4;
}

// ---------------------------------------------------------------------------
// W_recv [256,1024] -> WR_hi/WR_lo [1024 cols][256 k] (transposed, f16 split)
__global__ __launch_bounds__(64) void split_wr_kernel(const float* __restrict__ W,
                                                      f16* __restrict__ wrh,
                                                      f16* __restrict__ wrl) {
    int n = blockIdx.x;       // col 0..1023
    int t = threadIdx.x;      // 0..63
    f16x4 h4, l4;
#pragma unroll
    for (int j = 0; j < 4; ++j) {
        int k = t * 4 + j;
        float x = W[(size_t)k * DIN + n];
        f16 h, l; split_f32(x, h, l);
        h4[j] = h; l4[j] = l;
    }
    *(f16x4*)&wrh[(size_t)n * DEMB + t * 4] = h4;
    *(f16x4*)&wrl[(size_t)n * DEMB + t * 4] = l4;
}

// ---------------------------------------------------------------------------
__global__ __launch_bounds__(256) void split_cb_kernel(const float* __restrict__ cb,
                                                       f16* __restrict__ cbh,
                                                       f16* __restrict__ cbl) {
    int idx = (blockIdx.x * 256 + threadIdx.x) * 4;
    float4 v = *(const float4*)&cb[idx];
    f16x4 h4, l4;
    f16 h, l;
    split_f32(v.x, h, l); h4[0] = h; l4[0] = l;
    split_f32(v.y, h, l); h4[1] = h; l4[1] = l;
    split_f32(v.z, h, l); h4[2] = h; l4[2] = l;
    split_f32(v.w, h, l); h4[3] = h; l4[3] = l;
    *(f16x4*)&cbh[idx] = h4;
    *(f16x4*)&cbl[idx] = l4;
}

// ---------------------------------------------------------------------------
// z = input @ W_send + b_send via f16x3 MFMA (32x32x16), + z hi/lo split out.
// v5 = v4 (64x64 tile, BK=64, 256 thr, 32 KB single-buf, 4 blocks/CU) +
//  * bijective XCD-gather swizzle: all 4 col-siblings of a row panel land on
//    the SAME XCD (same L2) -> input fetched once (fixes v4's 2x FETCH).
//  * A-prefetch into regs before compute (T14): HBM latency hidden by MFMA.
// K-seg order & MFMA sequence identical to v1..v4 -> z bit-identical.
__global__ __launch_bounds__(256, 4) void gemm1_mfma(const float* __restrict__ in,
                                                     const f16* __restrict__ wth,
                                                     const f16* __restrict__ wtl,
                                                     const float* __restrict__ bsend,
                                                     float* __restrict__ z,
                                                     f16* __restrict__ zh,
                                                     f16* __restrict__ zl) {
    // f16 offsets: Ah [0,4096) Al [4096,8192) Bh [8192,12288) Bl [12288,16384)
    __shared__ f16 sm[16384];   // 32 KB
    const int tid = threadIdx.x;
    const int wave = tid >> 6, lane = tid & 63;
    const int half = lane >> 5, l31 = lane & 31;
    const int wr = wave >> 1, wc = wave & 1;

    // XCD-gather decode: L = (by&7) + 8*(bx + 4*(by>>3)); bijective on 1024.
    const int L = blockIdx.x;
    const int v = L >> 3;
    const int bx = v & 3;
    const int by = (L & 7) + 8 * (v >> 2);
    const int rowBase = by * 64;
    const int colBase = bx * 64;

    const int sr  = tid >> 2;    // staging row 0..63
    const int skq = tid & 3;     // staging k-quarter (16 floats)
    const int sr7 = sr & 7;

    f32x16 accm = {};
    f32x16 accx = {};
    float4 av[4];

    auto stageB = [&](int ks) {
#pragma unroll
        for (int i = 0; i < 4; ++i) {
            const int q  = wave * 4 + i;          // 0..15
            const int hl = q >> 3;
            const int cq = (q & 7) * 8;           // col group base
            const int col = cq + (lane >> 3);
            const int p  = lane & 7;              // physical 16B slot
            const int s  = p ^ (col & 7);         // logical slot (inv swizzle)
            const f16* src = (hl ? wtl : wth)
                           + (size_t)(colBase + col) * DIN + ks + s * 8;
            f16* dst = sm + 8192 + hl * 4096 + cq * 64;   // wave-uniform
            __builtin_amdgcn_global_load_lds(
                (const __attribute__((address_space(1))) void*)src,
                (__attribute__((address_space(3))) void*)dst, 16, 0, 0);
        }
    };

    auto loadA = [&](int ks) {
        const float* srcp = &in[(size_t)(rowBase + sr) * DIN + ks + skq * 16];
        av[0] = ((const float4*)srcp)[0];
        av[1] = ((const float4*)srcp)[1];
        av[2] = ((const float4*)srcp)[2];
        av[3] = ((const float4*)srcp)[3];
    };

    auto writeA = [&]() {
        f16 h, l;
        f16x8 h8, l8;
        split_f32(av[0].x, h, l); h8[0] = h; l8[0] = l;
        split_f32(av[0].y, h, l); h8[1] = h; l8[1] = l;
        split_f32(av[0].z, h, l); h8[2] = h; l8[2] = l;
        split_f32(av[0].w, h, l); h8[3] = h; l8[3] = l;
        split_f32(av[1].x, h, l); h8[4] = h; l8[4] = l;
        split_f32(av[1].y, h, l); h8[5] = h; l8[5] = l;
        split_f32(av[1].z, h, l); h8[6] = h; l8[6] = l;
        split_f32(av[1].w, h, l); h8[7] = h; l8[7] = l;
        const int o0 = sr * 64 + (((2 * skq + 0) ^ sr7) << 3);
        *(f16x8*)&sm[o0] = h8;
        *(f16x8*)&sm[4096 + o0] = l8;

        split_f32(av[2].x, h, l); h8[0] = h; l8[0] = l;
        split_f32(av[2].y, h, l); h8[1] = h; l8[1] = l;
        split_f32(av[2].z, h, l); h8[2] = h; l8[2] = l;
        split_f32(av[2].w, h, l); h8[3] = h; l8[3] = l;
        split_f32(av[3].x, h, l); h8[4] = h; l8[4] = l;
        split_f32(av[3].y, h, l); h8[5] = h; l8[5] = l;
        split_f32(av[3].z, h, l); h8[6] = h; l8[6] = l;
        split_f32(av[3].w, h, l); h8[7] = h; l8[7] = l;
        const int o1 = sr * 64 + (((2 * skq + 1) ^ sr7) << 3);
        *(f16x8*)&sm[o1] = h8;
        *(f16x8*)&sm[4096 + o1] = l8;
    };

    // prologue: stage step 0
    stageB(0);
    loadA(0);
    writeA();
    __syncthreads();

    for (int step = 0; step < 16; ++step) {
        const bool pf = (step + 1) < 16;
        if (pf) loadA((step + 1) * 64);   // global->reg, hides under compute

        // ---- compute: 4 k-segs x 3 MFMA ----
        {
            const int r = wr * 32 + l31;
            const int c = wc * 32 + l31;
            const int r7 = r & 7, c7 = c & 7;
#pragma unroll
            for (int t = 0; t < 4; ++t) {
                const int sgi = t * 2 + half;
                const int aoff = r * 64 + ((sgi ^ r7) << 3);
                const int boff = c * 64 + ((sgi ^ c7) << 3);
                f16x8 a_h = *(const f16x8*)&sm[aoff];
                f16x8 a_l = *(const f16x8*)&sm[4096 + aoff];
                f16x8 b_h = *(const f16x8*)&sm[8192 + boff];
                f16x8 b_l = *(const f16x8*)&sm[12288 + boff];
                accm = __builtin_amdgcn_mfma_f32_32x32x16_f16(a_h, b_h, accm, 0, 0, 0);
                accx = __builtin_amdgcn_mfma_f32_32x32x16_f16(a_h, b_l, accx, 0, 0, 0);
                accx = __builtin_amdgcn_mfma_f32_32x32x16_f16(a_l, b_h, accx, 0, 0, 0);
            }
        }

        __syncthreads();   // compute done; LDS free
        if (pf) {
            stageB((step + 1) * 64);   // async glds into freed buffer
            writeA();                  // split+write the prefetched A regs
            __syncthreads();           // stage visible
        }
    }

    // ---- epilogue ----
    {
        const int col = colBase + wc * 32 + l31;
        const float bb = bsend[col];
#pragma unroll
        for (int reg = 0; reg < 16; ++reg) {
            const int row = rowBase + wr * 32 + (reg & 3) + 8 * (reg >> 2) + 4 * half;
            const float zv = accm[reg] + INV2048 * accx[reg] + bb;
            const size_t o = (size_t)row * DEMB + col;
            z[o] = zv;
            f16 h = (f16)zv;
            zh[o] = h;
            zl[o] = (f16)((zv - (float)h) * 2048.0f);
        }
    }
}

// ---------------------------------------------------------------------------
// R = codebook @ W_recv via f16x3 MFMA (replaces naive fp32 gemm64).
// A = cbh/cbl [1024][256], B = wrh/wrl [1024 cols][256]. 64x64 tile, BK=64,
// 4 steps, glds staging with XOR slot swizzle (same proven pattern).
__global__ __launch_bounds__(256, 2) void gemm2_mfma(const f16* __restrict__ cbh,
                                                     const f16* __restrict__ cbl,
                                                     const f16* __restrict__ wrh,
                                                     const f16* __restrict__ wrl,
                                                     float* __restrict__ R) {
    __shared__ f16 sm[16384];  // Ah[0) Al[4096) Bh[8192) Bl[12288)
    const int tid = threadIdx.x;
    const int wave = tid >> 6, lane = tid & 63;
    const int half = lane >> 5, l31 = lane & 31;
    const int wr = wave >> 1, wc = wave & 1;
    const int rowBase = blockIdx.y * 64;   // cb rows
    const int colBase = blockIdx.x * 64;   // W_recv cols

    f32x16 accm = {}, accx = {};

    for (int step = 0; step < 4; ++step) {
        const int ks = step * 64;
        __syncthreads();                   // prior compute done (no-op 1st)
#pragma unroll
        for (int i = 0; i < 8; ++i) {
            const int q   = wave * 8 + i;  // 0..31 (wave-uniform)
            const int arr = q >> 3;        // 0 Ah, 1 Al, 2 Bh, 3 Bl
            const int grp = q & 7;         // 8-row group
            const int r   = grp * 8 + (lane >> 3);
            const int p   = lane & 7;
            const int s   = p ^ (r & 7);   // inverse swizzle on source
            const f16* basep = (arr == 0) ? cbh : (arr == 1) ? cbl
                             : (arr == 2) ? wrh : wrl;
            const int rowg = ((arr >= 2) ? colBase : rowBase) + r;
            const f16* src = basep + (size_t)rowg * DEMB + ks + s * 8;
            f16* dst = sm + arr * 4096 + grp * 512;   // wave-uniform
            __builtin_amdgcn_global_load_lds(
                (const __attribute__((address_space(1))) void*)src,
                (__attribute__((address_space(3))) void*)dst, 16, 0, 0);
        }
        __syncthreads();
#pragma unroll
        for (int t = 0; t < 4; ++t) {
            const int sgi = t * 2 + half;
            const int ar = wr * 32 + l31;
            const int bc = wc * 32 + l31;
            const int aoff = ar * 64 + ((sgi ^ (ar & 7)) << 3);
            const int boff = bc * 64 + ((sgi ^ (bc & 7)) << 3);
            f16x8 a_h = *(const f16x8*)&sm[aoff];
            f16x8 a_l = *(const f16x8*)&sm[4096 + aoff];
            f16x8 b_h = *(const f16x8*)&sm[8192 + boff];
            f16x8 b_l = *(const f16x8*)&sm[12288 + boff];
            accm = __builtin_amdgcn_mfma_f32_32x32x16_f16(a_h, b_h, accm, 0, 0, 0);
            accx = __builtin_amdgcn_mfma_f32_32x32x16_f16(a_h, b_l, accx, 0, 0, 0);
            accx = __builtin_amdgcn_mfma_f32_32x32x16_f16(a_l, b_h, accx, 0, 0, 0);
        }
    }

    const int col = colBase + wc * 32 + l31;
#pragma unroll
    for (int reg = 0; reg < 16; ++reg) {
        const int row = rowBase + wr * 32 + (reg & 3) + 8 * (reg >> 2) + 4 * half;
        R[(size_t)row * DIN + col] = accm[reg] + INV2048 * accx[reg];
    }
}

// ---------------------------------------------------------------------------
// cov + argmin via f16x3 MFMA (round-1 structure) + XCD-gather swizzle:
// the 4 code-chunk siblings sharing one z row-panel land on the same XCD.
__device__ __forceinline__ void cov_stage(const f16* __restrict__ cbh,
                                          const f16* __restrict__ cbl,
                                          f16* sC, int buf, int codeBase,
                                          int wave, int lane) {
#pragma unroll
    for (int i = 0; i < 8; ++i) {
        const int seg = wave * 8 + i;          // 0..31
        const int hl  = seg >> 4;              // 0: hi array, 1: lo array
        const int rp  = seg & 15;              // row pair
        const int r   = rp * 2 + (lane >> 5);  // 0..31 (per-lane row)
        const f16* src = (hl ? cbl : cbh)
                       + (size_t)(codeBase + r) * DEMB
                       + (((lane & 31) ^ r) << 3);
        f16* dst = sC + (((buf << 1) + hl) * 32 + rp * 2) * DEMB;  // wave-uniform
        __builtin_amdgcn_global_load_lds(
            (const __attribute__((address_space(1))) void*)src,
            (__attribute__((address_space(3))) void*)dst,
            16, 0, 0);
    }
}

__global__ __launch_bounds__(256, 2) void cov_mfma_kernel(const f16* __restrict__ zh,
                                                          const f16* __restrict__ zl,
                                                          const f16* __restrict__ cbh,
                                                          const f16* __restrict__ cbl,
                                                          const float* __restrict__ sqr,
                                                          u64* __restrict__ keys) {
    __shared__ f16 sC[2 * 2 * 32 * DEMB];   // 64 KB: [buf][hi/lo][code][dim swz]
    const int tid = threadIdx.x;
    const int wave = tid >> 6, lane = tid & 63;
    const int half = lane >> 5, l31 = lane & 31;

    // XCD-gather decode (512 blocks): bx = code chunk 0..3, by = row panel 0..127
    const int L = blockIdx.x;
    const int v = L >> 3;
    const int bx = v & 3;
    const int by = (L & 7) + 8 * (v >> 2);

    const int rowBase = by * 128 + wave * 32;
    const int myRow = rowBase + l31;
    const int cb0 = bx * (COV_CHUNKS * 32);   // 256 codes per block

    cov_stage(cbh, cbl, sC, 0, cb0, wave, lane);

    f16x8 a_h[16], a_l[16];
#pragma unroll
    for (int t = 0; t < 16; ++t) {
        size_t o = (size_t)myRow * DEMB + t * 16 + half * 8;
        a_h[t] = *(const f16x8*)&zh[o];
        a_l[t] = *(const f16x8*)&zl[o];
    }

    float runv[16];
    int   runc[16];
#pragma unroll
    for (int r = 0; r < 16; ++r) { runv[r] = 3.4e38f; runc[r] = 0; }

    for (int cc = 0; cc < COV_CHUNKS; ++cc) {
        __syncthreads();
        if (cc + 1 < COV_CHUNKS)
            cov_stage(cbh, cbl, sC, (cc + 1) & 1, cb0 + (cc + 1) * 32, wave, lane);

        const f16* Ch = sC + ((cc & 1) * 2 + 0) * 32 * DEMB;
        const f16* Cl = sC + ((cc & 1) * 2 + 1) * 32 * DEMB;

        f32x16 accm = {};
        f32x16 accx = {};
#pragma unroll
        for (int t = 0; t < 16; ++t) {
            const int seg = t * 2 + half;
            const int p = ((seg ^ l31) << 3);
            f16x8 b_h = *(const f16x8*)&Ch[l31 * DEMB + p];
            f16x8 b_l = *(const f16x8*)&Cl[l31 * DEMB + p];
            accm = __builtin_amdgcn_mfma_f32_32x32x16_f16(a_h[t], b_h, accm, 0, 0, 0);
            accx = __builtin_amdgcn_mfma_f32_32x32x16_f16(a_h[t], b_l, accx, 0, 0, 0);
            accx = __builtin_amdgcn_mfma_f32_32x32x16_f16(a_l[t], b_h, accx, 0, 0, 0);
        }

        const int code = cb0 + cc * 32 + l31;
        const float sqv = sqr[code];
#pragma unroll
        for (int r = 0; r < 16; ++r) {
            float s = sqv - 2.0f * (accm[r] + INV2048 * accx[r]);
            if (s < runv[r]) { runv[r] = s; runc[r] = code; }
        }
    }

#pragma unroll
    for (int r = 0; r < 16; ++r) {
        float v2 = runv[r]; int ci = runc[r];
        for (int off = 16; off > 0; off >>= 1) {
            float ov = __shfl_down(v2, off, 32);
            int   oc = __shfl_down(ci, off, 32);
            if (ov < v2 || (ov == v2 && oc < ci)) { v2 = ov; ci = oc; }
        }
        if (l31 == 0) {
            int row = rowBase + (r & 3) + 8 * (r >> 2) + 4 * half;
            unsigned ub = __float_as_uint(v2);
            ub = (ub & 0x80000000u) ? ~ub : (ub | 0x80000000u);
            u64 key = ((u64)ub << 32) | (unsigned)ci;
            atomicMin(&keys[row], key);
        }
    }
}

// ---------------------------------------------------------------------------
// decode keys -> codes (+float codes out) and build histogram
__global__ __launch_bounds__(256) void decode_kernel(const u64* __restrict__ keys,
                                                     int* __restrict__ codes,
                                                     float* __restrict__ out_codes,
                                                     int* __restrict__ hist) {
    int r = blockIdx.x * 256 + threadIdx.x;
    int c = (int)(keys[r] & 0xFFFFFFFFull);
    codes[r] = c;
    out_codes[r] = (float)c;
    atomicAdd(&hist[c], 1);
}

// ---------------------------------------------------------------------------
// exclusive prefix over hist (1 block of 1024); also counts as float
__global__ __launch_bounds__(1024) void prefix_kernel(const int* __restrict__ hist,
                                                      int* __restrict__ offs,
                                                      float* __restrict__ countsf) {
    __shared__ int s[1024];
    int t = threadIdx.x;
    int v = hist[t];
    s[t] = v;
    countsf[t] = (float)v;
    __syncthreads();
    for (int d = 1; d < 1024; d <<= 1) {
        int x = (t >= d) ? s[t - d] : 0;
        __syncthreads();
        s[t] += x;
        __syncthreads();
    }
    offs[t] = s[t] - v;
}

// ---------------------------------------------------------------------------
__global__ __launch_bounds__(256) void fill_kernel(const int* __restrict__ codes,
                                                   const int* __restrict__ offs,
                                                   int* __restrict__ cursor,
                                                   int* __restrict__ list) {
    int r = blockIdx.x * 256 + threadIdx.x;
    int c = codes[r];
    int pos = offs[c] + atomicAdd(&cursor[c], 1);
    list[pos] = r;
}

// ---------------------------------------------------------------------------
// balanced segment-sum over the sorted list: 32 list entries per block,
// 256 thr = 1 dim each. Register partial per run; atomicAdd flush at run
// boundaries (wave-uniform). Also accumulates commitment loss.
__global__ __launch_bounds__(256) void upd_loss_kernel(const float* __restrict__ z,
                                                       const float* __restrict__ cb,
                                                       const int* __restrict__ list,
                                                       const int* __restrict__ codes,
                                                       float* __restrict__ upd,
                                                       float* __restrict__ loss) {
    __shared__ int srow[CHUNK];
    __shared__ int scode[CHUNK];
    const int tid = threadIdx.x;
    const int base = blockIdx.x * CHUNK;
    if (tid < CHUNK) {
        int r = list[base + tid];
        srow[tid] = r;
        scode[tid] = codes[r];
    }
    __syncthreads();

    int cur = scode[0];
    float cbv = cb[(size_t)cur * DEMB + tid];
    float acc = 0.f, lacc = 0.f;
    float zv = z[(size_t)srow[0] * DEMB + tid];
#pragma unroll 4
    for (int i = 0; i < CHUNK; ++i) {
        float znext = (i + 1 < CHUNK) ? z[(size_t)srow[i + 1] * DEMB + tid] : 0.f;
        int c = scode[i];
        if (c != cur) {                         // wave-uniform branch
            atomicAdd(&upd[(size_t)cur * DEMB + tid], acc);
            acc = 0.f;
            cur = c;
            cbv = cb[(size_t)cur * DEMB + tid];
        }
        acc += zv;
        float d = zv - cbv;
        lacc += d * d;
        zv = znext;
    }
    atomicAdd(&upd[(size_t)cur * DEMB + tid], acc);

    __shared__ float red[256];
    red[tid] = lacc;
    __syncthreads();
    for (int s = 128; s > 0; s >>= 1) {
        if (tid < s) red[tid] += red[tid + s];
        __syncthreads();
    }
    if (tid == 0) atomicAdd(loss, red[0]);
}

// ---------------------------------------------------------------------------
__global__ __launch_bounds__(256) void recv_kernel(const float* __restrict__ R,
                                                   const float* __restrict__ brecv,
                                                   const int* __restrict__ codes,
                                                   float* __restrict__ out) {
    const int n = blockIdx.x;
    const int t = threadIdx.x;
    const int code = codes[n];
    float4 r = ((const float4*)(R + (size_t)code * DIN))[t];
    float4 b = ((const float4*)brecv)[t];
    ((float4*)(out + (size_t)n * DIN))[t] =
        make_float4(r.x + b.x, r.y + b.y, r.z + b.z, r.w + b.w);
}

// ---------------------------------------------------------------------------
__global__ __launch_bounds__(1024) void ema_small_kernel(const float* __restrict__ ema_size,
                                                         const float* __restrict__ counts,
                                                         const float* __restrict__ loss,
                                                         float* __restrict__ size_ws,
                                                         float* __restrict__ out) {
    __shared__ float rn[1024];
    __shared__ float re[1024];
    const int k = threadIdx.x;
    float c  = counts[k];
    float es = ema_size[k];
    float esn = es + ALPHA * (c - es);
    out[OUT_EMAS + k] = esn;
    float p = c * (1.0f / (float)NROWS);
    rn[k] = esn;
    re[k] = (p > 0.f) ? p * logf(p) : 0.f;
    __syncthreads();
    for (int s = 512; s > 0; s >>= 1) {
        if (k < s) { rn[k] += rn[k + s]; re[k] += re[k + s]; }
        __syncthreads();
    }
    float n = rn[0];
    float coef = n / (n + (float)KC * EPSV);
    size_ws[k] = coef * (esn + EPSV);
    if (k == 0) {
        out[OUT_ENT] = -re[0] / logf(2.0f);
        float l = loss[0];
        out[OUT_EMB] = l;
        out[OUT_COMMIT] = l;
    }
}

// ---------------------------------------------------------------------------
__global__ __launch_bounds__(256) void emav_kernel(const float* __restrict__ ema_vecs,
                                                   const float* __restrict__ upd,
                                                   const float* __restrict__ size_ws,
                                                   float* __restrict__ out) {
    int idx = blockIdx.x * 256 + threadIdx.x;
    float ev = ema_vecs[idx], uv = upd[idx];
    float evn = ev + ALPHA * (uv - ev);
    out[OUT_EMAV + idx] = evn;
    out[OUT_W + idx] = evn / size_ws[idx >> 8];
}

// ---------------------------------------------------------------------------
extern "C" void kernel_launch(void* const* d_in, const int* in_sizes, int n_in,
                              void* d_out, int out_size, void* d_ws, size_t ws_size,
                              hipStream_t stream) {
    const float* input    = (const float*)d_in[0];
    const float* W_send   = (const float*)d_in[1];
    const float* b_send   = (const float*)d_in[2];
    const float* W_recv   = (const float*)d_in[3];
    const float* b_recv   = (const float*)d_in[4];
    const float* codebook = (const float*)d_in[5];
    const float* ema_vecs = (const float*)d_in[6];
    const float* ema_size = (const float*)d_in[7];
    float* out = (float*)d_out;
    float* ws  = (float*)d_ws;
    int*   wsi = (int*)d_ws;

    f16* wth = (f16*)(ws + OFF_WTH);
    f16* wtl = (f16*)(ws + OFF_WTL);
    f16* cbh = (f16*)(ws + OFF_CBH);
    f16* cbl = (f16*)(ws + OFF_CBL);
    f16* zh  = (f16*)(ws + OFF_ZH);
    f16* zl  = (f16*)(ws + OFF_ZL);
    u64* keys = (u64*)(ws + OFF_KEYS);
    // wrh/wrl parked in ZH region (consumed by gemm2 before gemm1 writes zh)
    f16* wrh = (f16*)(ws + OFF_ZH);
    f16* wrl = (f16*)(ws + OFF_ZH + 131072);

    // zero upd+hist+cursor+loss; keys to all-ones
    (void)hipMemsetAsync(ws + OFF_UPD, 0, (size_t)ZERO_LEN * sizeof(float), stream);
    (void)hipMemsetAsync(ws + OFF_KEYS, 0xFF, (size_t)NROWS * sizeof(u64), stream);

    sqr_kernel<<<KC, 64, 0, stream>>>(codebook, ws + OFF_SQR);
    split_wt_kernel<<<DEMB, 256, 0, stream>>>(W_send, wth, wtl);
    split_cb_kernel<<<256, 256, 0, stream>>>(codebook, cbh, cbl);
    split_wr_kernel<<<DIN, 64, 0, stream>>>(W_recv, wrh, wrl);

    // R = codebook @ W_recv (f16x3 MFMA)
    gemm2_mfma<<<dim3(DIN / 64, KC / 64), 256, 0, stream>>>(
        cbh, cbl, wrh, wrl, ws + OFF_R);

    // z = input @ W_send + b_send (f16x3 MFMA) + fused hi/lo split
    gemm1_mfma<<<(DEMB / 64) * (NROWS / 64), 256, 0, stream>>>(
        input, wth, wtl, b_send, ws + OFF_Z, zh, zl);

    // cov + fused argmin (XCD-gather swizzled grid)
    cov_mfma_kernel<<<(KC / (COV_CHUNKS * 32)) * (NROWS / 128), 256, 0, stream>>>(
        zh, zl, cbh, cbl, ws + OFF_SQR, keys);

    decode_kernel<<<NROWS / 256, 256, 0, stream>>>(
        keys, wsi + OFF_CODES, out + OUT_CODES, wsi + OFF_HIST);

    prefix_kernel<<<1, 1024, 0, stream>>>(
        wsi + OFF_HIST, wsi + OFF_OFFS, ws + OFF_COUNTSF);

    fill_kernel<<<NROWS / 256, 256, 0, stream>>>(
        wsi + OFF_CODES, wsi + OFF_OFFS, wsi + OFF_CURSOR, wsi + OFF_LIST);

    upd_loss_kernel<<<NROWS / CHUNK, 256, 0, stream>>>(
        ws + OFF_Z, codebook, wsi + OFF_LIST, wsi + OFF_CODES,
        ws + OFF_UPD, ws + OFF_LOSS);

    recv_kernel<<<NROWS, 256, 0, stream>>>(
        ws + OFF_R, b_recv, wsi + OFF_CODES, out + OUT_X);

    ema_small_kernel<<<1, 1024, 0, stream>>>(
        ema_size, ws + OFF_COUNTSF, ws + OFF_LOSS, ws + OFF_SIZE, out);

    emav_kernel<<<KC, 256, 0, stream>>>(
        ema_vecs, ws + OFF_UPD, ws + OFF_SIZE, out);
}

// Round 6
// 249.352 us; speedup vs baseline: 1.1879x; 1.1035x over previous
//
#include <hip/hip_runtime.h>
#include <math.h>

#define NROWS 16384
#define DIN   1024
#define DEMB  256
#define KC    1024
#define ALPHA 0.01f
#define EPSV  1e-5f
#define INV2048 4.8828125e-4f
#define CHUNK 32
#define COV_CHUNKS 8

typedef _Float16 f16;
typedef __attribute__((ext_vector_type(4)))  _Float16 f16x4;
typedef __attribute__((ext_vector_type(8)))  _Float16 f16x8;
typedef __attribute__((ext_vector_type(16))) float    f32x16;
typedef unsigned long long u64;

// ---- workspace layout (float-element offsets, 16-aligned) ----
#define OFF_Z       0          // NROWS*DEMB = 4194304 (fp32 z)
#define OFF_R       4194304    // KC*DIN = 1048576
#define OFF_SQR     5242880    // KC
#define OFF_ZH      5243904    // NROWS*DEMB f16 = 2097152 floats
#define OFF_ZL      7341056    // 2097152
#define OFF_WTH     9438208    // DEMB*DIN f16 = 131072 floats
#define OFF_WTL     9569280    // 131072
#define OFF_CBH     9700352    // KC*DEMB f16 = 131072 floats
#define OFF_CBL     9831424    // 131072
#define OFF_KEYS    9962496    // NROWS u64 = 32768 floats (init 0xFF by prep)
#define OFF_CODES   9995264    // NROWS ints
#define OFF_LIST    10011648   // NROWS ints (bucketed row ids)
#define OFF_OFFS    10028032   // KC ints (exclusive prefix)
#define OFF_UPD     10029056   // KC*DEMB = 262144 (zeroed by prep)
#define OFF_HIST    10291200   // KC ints   (zeroed by prep)
#define OFF_CURSOR  10292224   // KC ints   (zeroed by prep)
#define OFF_LOSS    10293248   // 16        (zeroed by prep)
#define OFF_COUNTSF 10293264   // KC floats
#define OFF_SIZE    10294288   // KC floats
// wrh/wrl (split W_recv) parked in ZH region: consumed by gemm2 BEFORE
// gemm1 overwrites zh.

// ---- output layout (float-element offsets) ----
#define OUT_X      0           // NROWS*DIN
#define OUT_CODES  16777216    // NROWS
#define OUT_EMB    16793600
#define OUT_COMMIT 16793601
#define OUT_ENT    16793602
#define OUT_EMAV   16793603    // KC*DEMB
#define OUT_EMAS   17055747    // KC
#define OUT_W      17056771    // KC*DEMB

__device__ __forceinline__ void split_f32(float x, f16& h, f16& l) {
    h = (f16)x;
    l = (f16)((x - (float)h) * 2048.0f);
}

// ---------------------------------------------------------------------------
// prep: all preprocessing + buffer init in ONE dispatch (replaces sqr_kernel,
// split_wt, split_cb, split_wr, and both hipMemsetAsync calls).
//  blocks [   0, 256): split_wt   W_send[1024,256] -> wth/wtl [256][1024]
//  blocks [ 256, 512): split_cb   codebook -> cbh/cbl (linear)
//  blocks [ 512, 768): split_wr   W_recv[256,1024] -> wrh/wrl [1024][256]
//  blocks [ 768,1024): sqr        row norms of codebook
//  blocks [1024,1280): zero UPD (262144 floats)
//  block   1280      : zero HIST+CURSOR+LOSS
//  blocks [1281,1345): keys = 0xFF..
__global__ __launch_bounds__(256) void prep_kernel(const float* __restrict__ W_send,
                                                   const float* __restrict__ W_recv,
                                                   const float* __restrict__ cb,
                                                   float* __restrict__ ws) {
    const int b = blockIdx.x;
    const int t = threadIdx.x;
    int* wsi = (int*)ws;

    if (b < 256) {                       // ---- split_wt ----
        f16* wth = (f16*)(ws + OFF_WTH);
        f16* wtl = (f16*)(ws + OFF_WTL);
        const int n = b;
        f16x4 h4, l4;
#pragma unroll
        for (int j = 0; j < 4; ++j) {
            int k = t * 4 + j;
            float x = W_send[(size_t)k * DEMB + n];
            f16 h, l; split_f32(x, h, l);
            h4[j] = h; l4[j] = l;
        }
        *(f16x4*)&wth[(size_t)n * DIN + t * 4] = h4;
        *(f16x4*)&wtl[(size_t)n * DIN + t * 4] = l4;
    } else if (b < 512) {                // ---- split_cb ----
        f16* cbh = (f16*)(ws + OFF_CBH);
        f16* cbl = (f16*)(ws + OFF_CBL);
        int idx = ((b - 256) * 256 + t) * 4;
        float4 v = *(const float4*)&cb[idx];
        f16x4 h4, l4;
        f16 h, l;
        split_f32(v.x, h, l); h4[0] = h; l4[0] = l;
        split_f32(v.y, h, l); h4[1] = h; l4[1] = l;
        split_f32(v.z, h, l); h4[2] = h; l4[2] = l;
        split_f32(v.w, h, l); h4[3] = h; l4[3] = l;
        *(f16x4*)&cbh[idx] = h4;
        *(f16x4*)&cbl[idx] = l4;
    } else if (b < 768) {                // ---- split_wr ----
        f16* wrh = (f16*)(ws + OFF_ZH);
        f16* wrl = (f16*)(ws + OFF_ZH + 131072);
        const int n = (b - 512) * 4 + (t >> 6);   // col 0..1023
        const int lane = t & 63;
        f16x4 h4, l4;
#pragma unroll
        for (int j = 0; j < 4; ++j) {
            int k = lane * 4 + j;
            float x = W_recv[(size_t)k * DIN + n];
            f16 h, l; split_f32(x, h, l);
            h4[j] = h; l4[j] = l;
        }
        *(f16x4*)&wrh[(size_t)n * DEMB + lane * 4] = h4;
        *(f16x4*)&wrl[(size_t)n * DEMB + lane * 4] = l4;
    } else if (b < 1024) {               // ---- sqr ----
        float* sqr = ws + OFF_SQR;
        const int k = (b - 768) * 4 + (t >> 6);
        const int lane = t & 63;
        float4 v = ((const float4*)cb)[k * 64 + lane];
        float s = v.x * v.x + v.y * v.y + v.z * v.z + v.w * v.w;
        for (int off = 32; off > 0; off >>= 1) s += __shfl_down(s, off, 64);
        if (lane == 0) sqr[k] = s;
    } else if (b < 1280) {               // ---- zero UPD ----
        float4 zed = make_float4(0.f, 0.f, 0.f, 0.f);
        *(float4*)&ws[OFF_UPD + (size_t)(b - 1024) * 1024 + t * 4] = zed;
    } else if (b == 1280) {              // ---- zero HIST+CURSOR+LOSS ----
#pragma unroll
        for (int j = 0; j < 4; ++j) {
            wsi[OFF_HIST + t * 4 + j] = 0;
            wsi[OFF_CURSOR + t * 4 + j] = 0;
        }
        if (t < 16) ws[OFF_LOSS + t] = 0.f;
    } else {                             // ---- keys = all-ones ----
        u64* keys = (u64*)(ws + OFF_KEYS);
        keys[(b - 1281) * 256 + t] = ~0ull;
    }
}

// ---------------------------------------------------------------------------
// z = input @ W_send + b_send via f16x3 MFMA (32x32x16), + z hi/lo split out.
// v6 = round-2 structure (best measured: 128x128 tile, 512 thr, BK=64,
//      double-buffered 128 KB LDS, 24 MFMA/wave/step, async glds B + reg-
//      staged write-late A) + XCD-gather block swizzle (round-5 proven:
//      both col-siblings of a row panel -> same XCD L2, input fetched once).
// K accumulation order identical to all prior versions -> z bit-identical.
__global__ __launch_bounds__(512) void gemm1_mfma(const float* __restrict__ in,
                                                  const f16* __restrict__ wth,
                                                  const f16* __restrict__ wtl,
                                                  const float* __restrict__ bsend,
                                                  float* __restrict__ z,
                                                  f16* __restrict__ zh,
                                                  f16* __restrict__ zl) {
    // [buf][A=0/B=1][h/l][row 128][k 64] f16 = 131072 B
    __shared__ f16 sm[2 * 2 * 2 * 128 * 64];
    const int tid = threadIdx.x;
    const int wave = tid >> 6, lane = tid & 63;
    const int half = lane >> 5, l31 = lane & 31;
    const int wrow = wave >> 2, wcol = wave & 3;

    // XCD-gather: L = (by&7) + 8*(bx + 2*(by>>3)); bijective on 256.
    const int L = blockIdx.x;
    const int v = L >> 3;
    const int bx = v & 1;
    const int by = (L & 7) + 8 * (v >> 1);
    const int rowBase = by * 128;
    const int colBase = bx * 128;

    const int sr  = tid >> 2;    // staging row 0..127
    const int skq = tid & 3;     // staging k-quarter (16 f16)
    const int sr7 = sr & 7;

    f32x16 accm[2] = {};
    f32x16 accx[2] = {};

    // --- B async stage: chunk q = wave*4+i covers [hl][8 cols][8 slots] ---
    auto stageB = [&](int buf, int ks) {
#pragma unroll
        for (int i = 0; i < 4; ++i) {
            const int q  = wave * 4 + i;            // 0..31
            const int hl = q >> 4;
            const int c  = (q & 15) * 8 + (lane >> 3);
            const int p  = lane & 7;                // physical 16B slot
            const int s  = p ^ (c & 7);             // logical slot (pre-swizzle src)
            const f16* src = (hl ? wtl : wth)
                           + (size_t)(colBase + c) * DIN + ks + s * 8;
            f16* dst = sm + buf * 32768 + 16384 + q * 512 + lane * 8; // uniform+lane*16B
            __builtin_amdgcn_global_load_lds(
                (const __attribute__((address_space(1))) void*)src,
                (__attribute__((address_space(3))) void*)dst, 16, 0, 0);
        }
    };

    auto loadA = [&](int ks, float4* av) {
        const float* src = &in[(size_t)(rowBase + sr) * DIN + ks + skq * 16];
#pragma unroll
        for (int j = 0; j < 4; ++j) av[j] = ((const float4*)src)[j];
    };

    auto writeA = [&](int buf, const float4* av) {
        f16* Abase = sm + buf * 32768;
#pragma unroll
        for (int q = 0; q < 2; ++q) {
            f16x8 h8, l8;
#pragma unroll
            for (int j = 0; j < 2; ++j) {
                float4 v4 = av[q * 2 + j];
                f16 h, l;
                split_f32(v4.x, h, l); h8[j * 4 + 0] = h; l8[j * 4 + 0] = l;
                split_f32(v4.y, h, l); h8[j * 4 + 1] = h; l8[j * 4 + 1] = l;
                split_f32(v4.z, h, l); h8[j * 4 + 2] = h; l8[j * 4 + 2] = l;
                split_f32(v4.w, h, l); h8[j * 4 + 3] = h; l8[j * 4 + 3] = l;
            }
            const int s = skq * 2 + q;
            const int off = sr * 64 + ((s ^ sr7) << 3);
            *(f16x8*)&Abase[off] = h8;
            *(f16x8*)&Abase[8192 + off] = l8;
        }
    };

    auto compute = [&](int buf) {
        const f16* Ah = sm + buf * 32768;
        const f16* Al = Ah + 8192;
        const f16* Bh = Ah + 16384;
        const f16* Bl = Ah + 24576;
        const int c  = wcol * 32 + l31;
        const int c7 = c & 7;
#pragma unroll
        for (int t4 = 0; t4 < 4; ++t4) {
            const int s = t4 * 2 + half;
            f16x8 a_h[2], a_l[2];
#pragma unroll
            for (int rt = 0; rt < 2; ++rt) {
                const int r = wrow * 64 + rt * 32 + l31;
                const int off = r * 64 + ((s ^ (r & 7)) << 3);
                a_h[rt] = *(const f16x8*)&Ah[off];
                a_l[rt] = *(const f16x8*)&Al[off];
            }
            const int boff = c * 64 + ((s ^ c7) << 3);
            f16x8 b_h = *(const f16x8*)&Bh[boff];
            f16x8 b_l = *(const f16x8*)&Bl[boff];
#pragma unroll
            for (int rt = 0; rt < 2; ++rt) {
                accm[rt] = __builtin_amdgcn_mfma_f32_32x32x16_f16(a_h[rt], b_h, accm[rt], 0, 0, 0);
                accx[rt] = __builtin_amdgcn_mfma_f32_32x32x16_f16(a_h[rt], b_l, accx[rt], 0, 0, 0);
                accx[rt] = __builtin_amdgcn_mfma_f32_32x32x16_f16(a_l[rt], b_h, accx[rt], 0, 0, 0);
            }
        }
    };

    // prologue: stage K-step 0 into buf 0
    stageB(0, 0);
    {
        float4 av[4];
        loadA(0, av);
        writeA(0, av);
    }
    __syncthreads();

    int cur = 0;
    for (int step = 0; step < 16; ++step) {
        float4 av[4];
        const bool pf = (step + 1) < 16;
        if (pf) {
            stageB(cur ^ 1, (step + 1) * 64);   // async -> other buffer
            loadA((step + 1) * 64, av);         // HBM latency hides under compute
        }
        compute(cur);
        if (pf) writeA(cur ^ 1, av);            // write-late (T14)
        __syncthreads();                        // drains vmcnt/lgkm; buffers swap
        cur ^= 1;
    }

#pragma unroll
    for (int rt = 0; rt < 2; ++rt) {
        const int col = colBase + wcol * 32 + l31;
        const float bb = bsend[col];
#pragma unroll
        for (int reg = 0; reg < 16; ++reg) {
            const int row = rowBase + wrow * 64 + rt * 32 + (reg & 3) + 8 * (reg >> 2) + 4 * half;
            const float zv = accm[rt][reg] + INV2048 * accx[rt][reg] + bb;
            const size_t o = (size_t)row * DEMB + col;
            z[o] = zv;
            f16 h = (f16)zv;
            zh[o] = h;
            zl[o] = (f16)((zv - (float)h) * 2048.0f);
        }
    }
}

// ---------------------------------------------------------------------------
// R = codebook @ W_recv via f16x3 MFMA. 64x64 tile, BK=64, glds staging.
__global__ __launch_bounds__(256, 2) void gemm2_mfma(const f16* __restrict__ cbh,
                                                     const f16* __restrict__ cbl,
                                                     const f16* __restrict__ wrh,
                                                     const f16* __restrict__ wrl,
                                                     float* __restrict__ R) {
    __shared__ f16 sm[16384];  // Ah[0) Al[4096) Bh[8192) Bl[12288)
    const int tid = threadIdx.x;
    const int wave = tid >> 6, lane = tid & 63;
    const int half = lane >> 5, l31 = lane & 31;
    const int wr = wave >> 1, wc = wave & 1;
    const int rowBase = blockIdx.y * 64;   // cb rows
    const int colBase = blockIdx.x * 64;   // W_recv cols

    f32x16 accm = {}, accx = {};

    for (int step = 0; step < 4; ++step) {
        const int ks = step * 64;
        __syncthreads();                   // prior compute done (no-op 1st)
#pragma unroll
        for (int i = 0; i < 8; ++i) {
            const int q   = wave * 8 + i;  // 0..31 (wave-uniform)
            const int arr = q >> 3;        // 0 Ah, 1 Al, 2 Bh, 3 Bl
            const int grp = q & 7;         // 8-row group
            const int r   = grp * 8 + (lane >> 3);
            const int p   = lane & 7;
            const int s   = p ^ (r & 7);   // inverse swizzle on source
            const f16* basep = (arr == 0) ? cbh : (arr == 1) ? cbl
                             : (arr == 2) ? wrh : wrl;
            const int rowg = ((arr >= 2) ? colBase : rowBase) + r;
            const f16* src = basep + (size_t)rowg * DEMB + ks + s * 8;
            f16* dst = sm + arr * 4096 + grp * 512;   // wave-uniform
            __builtin_amdgcn_global_load_lds(
                (const __attribute__((address_space(1))) void*)src,
                (__attribute__((address_space(3))) void*)dst, 16, 0, 0);
        }
        __syncthreads();
#pragma unroll
        for (int t = 0; t < 4; ++t) {
            const int sgi = t * 2 + half;
            const int ar = wr * 32 + l31;
            const int bc = wc * 32 + l31;
            const int aoff = ar * 64 + ((sgi ^ (ar & 7)) << 3);
            const int boff = bc * 64 + ((sgi ^ (bc & 7)) << 3);
            f16x8 a_h = *(const f16x8*)&sm[aoff];
            f16x8 a_l = *(const f16x8*)&sm[4096 + aoff];
            f16x8 b_h = *(const f16x8*)&sm[8192 + boff];
            f16x8 b_l = *(const f16x8*)&sm[12288 + boff];
            accm = __builtin_amdgcn_mfma_f32_32x32x16_f16(a_h, b_h, accm, 0, 0, 0);
            accx = __builtin_amdgcn_mfma_f32_32x32x16_f16(a_h, b_l, accx, 0, 0, 0);
            accx = __builtin_amdgcn_mfma_f32_32x32x16_f16(a_l, b_h, accx, 0, 0, 0);
        }
    }

    const int col = colBase + wc * 32 + l31;
#pragma unroll
    for (int reg = 0; reg < 16; ++reg) {
        const int row = rowBase + wr * 32 + (reg & 3) + 8 * (reg >> 2) + 4 * half;
        R[(size_t)row * DIN + col] = accm[reg] + INV2048 * accx[reg];
    }
}

// ---------------------------------------------------------------------------
// cov + argmin via f16x3 MFMA (round-5 version, XCD-gather swizzle)
__device__ __forceinline__ void cov_stage(const f16* __restrict__ cbh,
                                          const f16* __restrict__ cbl,
                                          f16* sC, int buf, int codeBase,
                                          int wave, int lane) {
#pragma unroll
    for (int i = 0; i < 8; ++i) {
        const int seg = wave * 8 + i;          // 0..31
        const int hl  = seg >> 4;              // 0: hi array, 1: lo array
        const int rp  = seg & 15;              // row pair
        const int r   = rp * 2 + (lane >> 5);  // 0..31 (per-lane row)
        const f16* src = (hl ? cbl : cbh)
                       + (size_t)(codeBase + r) * DEMB
                       + (((lane & 31) ^ r) << 3);
        f16* dst = sC + (((buf << 1) + hl) * 32 + rp * 2) * DEMB;  // wave-uniform
        __builtin_amdgcn_global_load_lds(
            (const __attribute__((address_space(1))) void*)src,
            (__attribute__((address_space(3))) void*)dst,
            16, 0, 0);
    }
}

__global__ __launch_bounds__(256, 2) void cov_mfma_kernel(const f16* __restrict__ zh,
                                                          const f16* __restrict__ zl,
                                                          const f16* __restrict__ cbh,
                                                          const f16* __restrict__ cbl,
                                                          const float* __restrict__ sqr,
                                                          u64* __restrict__ keys) {
    __shared__ f16 sC[2 * 2 * 32 * DEMB];   // 64 KB: [buf][hi/lo][code][dim swz]
    const int tid = threadIdx.x;
    const int wave = tid >> 6, lane = tid & 63;
    const int half = lane >> 5, l31 = lane & 31;

    // XCD-gather decode (512 blocks): bx = code chunk 0..3, by = row panel 0..127
    const int L = blockIdx.x;
    const int v = L >> 3;
    const int bx = v & 3;
    const int by = (L & 7) + 8 * (v >> 2);

    const int rowBase = by * 128 + wave * 32;
    const int myRow = rowBase + l31;
    const int cb0 = bx * (COV_CHUNKS * 32);   // 256 codes per block

    cov_stage(cbh, cbl, sC, 0, cb0, wave, lane);

    f16x8 a_h[16], a_l[16];
#pragma unroll
    for (int t = 0; t < 16; ++t) {
        size_t o = (size_t)myRow * DEMB + t * 16 + half * 8;
        a_h[t] = *(const f16x8*)&zh[o];
        a_l[t] = *(const f16x8*)&zl[o];
    }

    float runv[16];
    int   runc[16];
#pragma unroll
    for (int r = 0; r < 16; ++r) { runv[r] = 3.4e38f; runc[r] = 0; }

    for (int cc = 0; cc < COV_CHUNKS; ++cc) {
        __syncthreads();
        if (cc + 1 < COV_CHUNKS)
            cov_stage(cbh, cbl, sC, (cc + 1) & 1, cb0 + (cc + 1) * 32, wave, lane);

        const f16* Ch = sC + ((cc & 1) * 2 + 0) * 32 * DEMB;
        const f16* Cl = sC + ((cc & 1) * 2 + 1) * 32 * DEMB;

        f32x16 accm = {};
        f32x16 accx = {};
#pragma unroll
        for (int t = 0; t < 16; ++t) {
            const int seg = t * 2 + half;
            const int p = ((seg ^ l31) << 3);
            f16x8 b_h = *(const f16x8*)&Ch[l31 * DEMB + p];
            f16x8 b_l = *(const f16x8*)&Cl[l31 * DEMB + p];
            accm = __builtin_amdgcn_mfma_f32_32x32x16_f16(a_h[t], b_h, accm, 0, 0, 0);
            accx = __builtin_amdgcn_mfma_f32_32x32x16_f16(a_h[t], b_l, accx, 0, 0, 0);
            accx = __builtin_amdgcn_mfma_f32_32x32x16_f16(a_l[t], b_h, accx, 0, 0, 0);
        }

        const int code = cb0 + cc * 32 + l31;
        const float sqv = sqr[code];
#pragma unroll
        for (int r = 0; r < 16; ++r) {
            float s = sqv - 2.0f * (accm[r] + INV2048 * accx[r]);
            if (s < runv[r]) { runv[r] = s; runc[r] = code; }
        }
    }

#pragma unroll
    for (int r = 0; r < 16; ++r) {
        float v2 = runv[r]; int ci = runc[r];
        for (int off = 16; off > 0; off >>= 1) {
            float ov = __shfl_down(v2, off, 32);
            int   oc = __shfl_down(ci, off, 32);
            if (ov < v2 || (ov == v2 && oc < ci)) { v2 = ov; ci = oc; }
        }
        if (l31 == 0) {
            int row = rowBase + (r & 3) + 8 * (r >> 2) + 4 * half;
            unsigned ub = __float_as_uint(v2);
            ub = (ub & 0x80000000u) ? ~ub : (ub | 0x80000000u);
            u64 key = ((u64)ub << 32) | (unsigned)ci;
            atomicMin(&keys[row], key);
        }
    }
}

// ---------------------------------------------------------------------------
// decode keys -> codes (+float codes out) and build histogram
__global__ __launch_bounds__(256) void decode_kernel(const u64* __restrict__ keys,
                                                     int* __restrict__ codes,
                                                     float* __restrict__ out_codes,
                                                     int* __restrict__ hist) {
    int r = blockIdx.x * 256 + threadIdx.x;
    int c = (int)(keys[r] & 0xFFFFFFFFull);
    codes[r] = c;
    out_codes[r] = (float)c;
    atomicAdd(&hist[c], 1);
}

// ---------------------------------------------------------------------------
// exclusive prefix over hist (1 block of 1024); also counts as float
__global__ __launch_bounds__(1024) void prefix_kernel(const int* __restrict__ hist,
                                                      int* __restrict__ offs,
                                                      float* __restrict__ countsf) {
    __shared__ int s[1024];
    int t = threadIdx.x;
    int v = hist[t];
    s[t] = v;
    countsf[t] = (float)v;
    __syncthreads();
    for (int d = 1; d < 1024; d <<= 1) {
        int x = (t >= d) ? s[t - d] : 0;
        __syncthreads();
        s[t] += x;
        __syncthreads();
    }
    offs[t] = s[t] - v;
}

// ---------------------------------------------------------------------------
__global__ __launch_bounds__(256) void fill_kernel(const int* __restrict__ codes,
                                                   const int* __restrict__ offs,
                                                   int* __restrict__ cursor,
                                                   int* __restrict__ list) {
    int r = blockIdx.x * 256 + threadIdx.x;
    int c = codes[r];
    int pos = offs[c] + atomicAdd(&cursor[c], 1);
    list[pos] = r;
}

// ---------------------------------------------------------------------------
// balanced segment-sum over the sorted list (unchanged)
__global__ __launch_bounds__(256) void upd_loss_kernel(const float* __restrict__ z,
                                                       const float* __restrict__ cb,
                                                       const int* __restrict__ list,
                                                       const int* __restrict__ codes,
                                                       float* __restrict__ upd,
                                                       float* __restrict__ loss) {
    __shared__ int srow[CHUNK];
    __shared__ int scode[CHUNK];
    const int tid = threadIdx.x;
    const int base = blockIdx.x * CHUNK;
    if (tid < CHUNK) {
        int r = list[base + tid];
        srow[tid] = r;
        scode[tid] = codes[r];
    }
    __syncthreads();

    int cur = scode[0];
    float cbv = cb[(size_t)cur * DEMB + tid];
    float acc = 0.f, lacc = 0.f;
    float zv = z[(size_t)srow[0] * DEMB + tid];
#pragma unroll 4
    for (int i = 0; i < CHUNK; ++i) {
        float znext = (i + 1 < CHUNK) ? z[(size_t)srow[i + 1] * DEMB + tid] : 0.f;
        int c = scode[i];
        if (c != cur) {                         // wave-uniform branch
            atomicAdd(&upd[(size_t)cur * DEMB + tid], acc);
            acc = 0.f;
            cur = c;
            cbv = cb[(size_t)cur * DEMB + tid];
        }
        acc += zv;
        float d = zv - cbv;
        lacc += d * d;
        zv = znext;
    }
    atomicAdd(&upd[(size_t)cur * DEMB + tid], acc);

    __shared__ float red[256];
    red[tid] = lacc;
    __syncthreads();
    for (int s = 128; s > 0; s >>= 1) {
        if (tid < s) red[tid] += red[tid + s];
        __syncthreads();
    }
    if (tid == 0) atomicAdd(loss, red[0]);
}

// ---------------------------------------------------------------------------
__global__ __launch_bounds__(256) void recv_kernel(const float* __restrict__ R,
                                                   const float* __restrict__ brecv,
                                                   const int* __restrict__ codes,
                                                   float* __restrict__ out) {
    const int n = blockIdx.x;
    const int t = threadIdx.x;
    const int code = codes[n];
    float4 r = ((const float4*)(R + (size_t)code * DIN))[t];
    float4 b = ((const float4*)brecv)[t];
    ((float4*)(out + (size_t)n * DIN))[t] =
        make_float4(r.x + b.x, r.y + b.y, r.z + b.z, r.w + b.w);
}

// ---------------------------------------------------------------------------
__global__ __launch_bounds__(1024) void ema_small_kernel(const float* __restrict__ ema_size,
                                                         const float* __restrict__ counts,
                                                         const float* __restrict__ loss,
                                                         float* __restrict__ size_ws,
                                                         float* __restrict__ out) {
    __shared__ float rn[1024];
    __shared__ float re[1024];
    const int k = threadIdx.x;
    float c  = counts[k];
    float es = ema_size[k];
    float esn = es + ALPHA * (c - es);
    out[OUT_EMAS + k] = esn;
    float p = c * (1.0f / (float)NROWS);
    rn[k] = esn;
    re[k] = (p > 0.f) ? p * logf(p) : 0.f;
    __syncthreads();
    for (int s = 512; s > 0; s >>= 1) {
        if (k < s) { rn[k] += rn[k + s]; re[k] += re[k + s]; }
        __syncthreads();
    }
    float n = rn[0];
    float coef = n / (n + (float)KC * EPSV);
    size_ws[k] = coef * (esn + EPSV);
    if (k == 0) {
        out[OUT_ENT] = -re[0] / logf(2.0f);
        float l = loss[0];
        out[OUT_EMB] = l;
        out[OUT_COMMIT] = l;
    }
}

// ---------------------------------------------------------------------------
__global__ __launch_bounds__(256) void emav_kernel(const float* __restrict__ ema_vecs,
                                                   const float* __restrict__ upd,
                                                   const float* __restrict__ size_ws,
                                                   float* __restrict__ out) {
    int idx = blockIdx.x * 256 + threadIdx.x;
    float ev = ema_vecs[idx], uv = upd[idx];
    float evn = ev + ALPHA * (uv - ev);
    out[OUT_EMAV + idx] = evn;
    out[OUT_W + idx] = evn / size_ws[idx >> 8];
}

// ---------------------------------------------------------------------------
extern "C" void kernel_launch(void* const* d_in, const int* in_sizes, int n_in,
                              void* d_out, int out_size, void* d_ws, size_t ws_size,
                              hipStream_t stream) {
    const float* input    = (const float*)d_in[0];
    const float* W_send   = (const float*)d_in[1];
    const float* b_send   = (const float*)d_in[2];
    const float* W_recv   = (const float*)d_in[3];
    const float* b_recv   = (const float*)d_in[4];
    const float* codebook = (const float*)d_in[5];
    const float* ema_vecs = (const float*)d_in[6];
    const float* ema_size = (const float*)d_in[7];
    float* out = (float*)d_out;
    float* ws  = (float*)d_ws;
    int*   wsi = (int*)d_ws;

    f16* wth = (f16*)(ws + OFF_WTH);
    f16* wtl = (f16*)(ws + OFF_WTL);
    f16* cbh = (f16*)(ws + OFF_CBH);
    f16* cbl = (f16*)(ws + OFF_CBL);
    f16* zh  = (f16*)(ws + OFF_ZH);
    f16* zl  = (f16*)(ws + OFF_ZL);
    u64* keys = (u64*)(ws + OFF_KEYS);
    // wrh/wrl parked in ZH region (consumed by gemm2 before gemm1 writes zh)
    f16* wrh = (f16*)(ws + OFF_ZH);
    f16* wrl = (f16*)(ws + OFF_ZH + 131072);

    // one prep dispatch: all splits + sqr + all buffer init (no memsets)
    prep_kernel<<<1345, 256, 0, stream>>>(W_send, W_recv, codebook, ws);

    // R = codebook @ W_recv (f16x3 MFMA)
    gemm2_mfma<<<dim3(DIN / 64, KC / 64), 256, 0, stream>>>(
        cbh, cbl, wrh, wrl, ws + OFF_R);

    // z = input @ W_send + b_send (f16x3 MFMA) + fused hi/lo split
    gemm1_mfma<<<(DEMB / 128) * (NROWS / 128), 512, 0, stream>>>(
        input, wth, wtl, b_send, ws + OFF_Z, zh, zl);

    // cov + fused argmin (XCD-gather swizzled grid)
    cov_mfma_kernel<<<(KC / (COV_CHUNKS * 32)) * (NROWS / 128), 256, 0, stream>>>(
        zh, zl, cbh, cbl, ws + OFF_SQR, keys);

    decode_kernel<<<NROWS / 256, 256, 0, stream>>>(
        keys, wsi + OFF_CODES, out + OUT_CODES, wsi + OFF_HIST);

    prefix_kernel<<<1, 1024, 0, stream>>>(
        wsi + OFF_HIST, wsi + OFF_OFFS, ws + OFF_COUNTSF);

    fill_kernel<<<NROWS / 256, 256, 0, stream>>>(
        wsi + OFF_CODES, wsi + OFF_OFFS, wsi + OFF_CURSOR, wsi + OFF_LIST);

    upd_loss_kernel<<<NROWS / CHUNK, 256, 0, stream>>>(
        ws + OFF_Z, codebook, wsi + OFF_LIST, wsi + OFF_CODES,
        ws + OFF_UPD, ws + OFF_LOSS);

    recv_kernel<<<NROWS, 256, 0, stream>>>(
        ws + OFF_R, b_recv, wsi + OFF_CODES, out + OUT_X);

    ema_small_kernel<<<1, 1024, 0, stream>>>(
        ema_size, ws + OFF_COUNTSF, ws + OFF_LOSS, ws + OFF_SIZE, out);

    emav_kernel<<<KC, 256, 0, stream>>>(
        ema_vecs, ws + OFF_UPD, ws + OFF_SIZE, out);
}